// Round 20
// baseline (299.247 us; speedup 1.0000x reference)
//
#include <hip/hip_runtime.h>
#include <hip/hip_bf16.h>
#include <cstdint>

// ---------------------------------------------------------------------------
// InteractionMHA, fp32 I/O, bf16-MFMA compute.
// Round-19 identity (verified: absmax unchanged): softmax rows sum to 1 =>
//   out = gelu(P @ (rep @ (Wm@Wv)^T + 1*bc^T)), bc = Wm@bv + bm.
// vgemmB projects rep directly through Wc=Wm@Wv; attn's PV accumulator IS the
// final output. Round-20 fixes r19's 2.7x WRITE amplification (112MB vs 42):
// fp32 output now leaves via an LDS bounce in 32-row rounds -> full-line
// stores (the r14-proven mechanism), gelu applied during the LDS write.
// ---------------------------------------------------------------------------

typedef short s16x8 __attribute__((ext_vector_type(8)));
typedef float f32x4 __attribute__((ext_vector_type(4)));

__device__ __forceinline__ s16x8 cvt8(const float* p) {
  float4 a0 = *(const float4*)p, a1 = *(const float4*)(p + 4);
  union { s16x8 v; __bf16 e[8]; } u;
  u.e[0] = (__bf16)a0.x; u.e[1] = (__bf16)a0.y; u.e[2] = (__bf16)a0.z; u.e[3] = (__bf16)a0.w;
  u.e[4] = (__bf16)a1.x; u.e[5] = (__bf16)a1.y; u.e[6] = (__bf16)a1.z; u.e[7] = (__bf16)a1.w;
  return u.v;
}
__device__ __forceinline__ float fast_gelu(float x) {
  float ax = fabsf(x);
  float t = 1.0f / (1.0f + 0.3275911f * (ax * 0.70710678f));
  float y = t * (0.254829592f + t * (-0.284496736f + t * (1.421413741f +
            t * (-1.453152027f + t * 1.061405429f))));
  float er = 1.0f - y * __expf(-0.5f * ax * ax);
  er = (x < 0.f) ? -er : er;
  return 0.5f * x * (1.0f + er);
}

__global__ void sentinel_kernel(float* out, float v) {
  if (threadIdx.x == 0 && blockIdx.x == 0) out[0] = v;
}

// ---------- scan + parallel XCD-affinity permutation (r18 proven) ----------
__global__ __launch_bounds__(512) void scan_kernel(
    const int* __restrict__ na, int* __restrict__ offs, int* __restrict__ perm,
    int B, int total, float* out)
{
  __shared__ int s32[512];
  __shared__ int s64[512];
  __shared__ uint4 sv[512];
  const int t = threadIdx.x;
  int v32 = 0, v64 = 0;
  if (t < B) {
    v32 = na[t];
    v64 = (int)((const long long*)na)[t];
  }
  s32[t] = v32; s64[t] = v64;
  __syncthreads();
  for (int o = 1; o < 512; o <<= 1) {
    int a = (t >= o) ? s32[t - o] : 0;
    int b = (t >= o) ? s64[t - o] : 0;
    __syncthreads();
    s32[t] += a; s64[t] += b;
    __syncthreads();
  }
  int tot32 = s32[B - 1], tot64 = s64[B - 1];
  bool ok32 = (tot32 == total), ok64 = (tot64 == total);
  int offv = ok32 ? (s32[t] - v32) : ok64 ? (s64[t] - v64) : 0;
  if (t < B) offs[t] = offv;
  if (t == 0) {
    offs[B] = ok32 ? tot32 : ok64 ? tot64 : 0;
    if (!ok32 && !ok64) out[0] = 31337.0f;
  }
  __syncthreads();

  const int key = (offv >> 7) & 7;
  uint4 oh = (uint4){0, 0, 0, 0};
  if (t < B) ((unsigned*)&oh)[key >> 1] = 1u << ((key & 1) * 16);
  sv[t] = oh;
  __syncthreads();
  for (int o = 1; o < 512; o <<= 1) {
    uint4 a = (t >= o) ? sv[t - o] : (uint4){0, 0, 0, 0};
    __syncthreads();
    sv[t].x += a.x; sv[t].y += a.y; sv[t].z += a.z; sv[t].w += a.w;
    __syncthreads();
  }
  uint4 totv = sv[B - 1];
  int count[8], cap[8];
  #pragma unroll
  for (int k = 0; k < 8; ++k) {
    count[k] = (((unsigned*)&totv)[k >> 1] >> ((k & 1) * 16)) & 0xFFFF;
    cap[k] = (k < B) ? ((B - 1 - k) / 8 + 1) : 0;
  }
  int rank = ((((unsigned*)&sv[t])[key >> 1] >> ((key & 1) * 16)) & 0xFFFF) - 1;
  bool lo = false;
  if (t < B) {
    if (rank < cap[key]) perm[key + 8 * rank] = t;
    else lo = true;
  }
  __syncthreads();
  s32[t] = lo ? 1 : 0;
  __syncthreads();
  for (int o = 1; o < 512; o <<= 1) {
    int a = (t >= o) ? s32[t - o] : 0;
    __syncthreads();
    s32[t] += a;
    __syncthreads();
  }
  if (lo) {
    int lr = s32[t] - 1;
    int used[8], eb = 0, k = 0, j = 0;
    #pragma unroll
    for (int q = 0; q < 8; ++q) used[q] = (count[q] < cap[q]) ? count[q] : cap[q];
    #pragma unroll
    for (int q = 0; q < 8; ++q) {
      int freeq = cap[q] - used[q];
      if (lr >= eb && lr < eb + freeq) { k = q; j = used[q] + (lr - eb); }
      eb += freeq;
    }
    perm[k + 8 * j] = t;
  }
}

// ---------- Wc = Wm @ Wv  (bf16 out; LDS-transposed Wv panel) --------------
__global__ __launch_bounds__(256) void wc_kernel(
    const float* __restrict__ Wm0, const float* __restrict__ Wv0,
    const float* __restrict__ Wm1, const float* __restrict__ Wv1,
    __bf16* __restrict__ Wcb0, __bf16* __restrict__ Wcb1)
{
  const int br = blockIdx.y;
  const float* Wm = br ? Wm1 : Wm0;
  const float* Wv = br ? Wv1 : Wv0;
  __bf16* Wcb = br ? Wcb1 : Wcb0;
  const int rt = blockIdx.x >> 1, ct = blockIdx.x & 1;
  __shared__ __bf16 Am[128][40];
  __shared__ __bf16 Bv[128][40];      // Bv[j][k] = Wv[kk+k][ct*128+j]
  const int t = threadIdx.x, lane = t & 63, w = t >> 6;
  const int wr = w >> 1, wc = w & 1;
  const int l15 = lane & 15, l4 = lane >> 4;

  f32x4 acc[4][4];
  for (int m = 0; m < 4; ++m)
    for (int nn = 0; nn < 4; ++nn) acc[m][nn] = (f32x4){0.f, 0.f, 0.f, 0.f};

  for (int kk = 0; kk < 256; kk += 32) {
    #pragma unroll
    for (int j = 0; j < 2; ++j) {
      int c = t + j * 256;
      int row = c >> 2, o0 = (c & 3) * 8;
      *(s16x8*)(&Am[row][o0]) = cvt8(Wm + (size_t)(rt * 128 + row) * 256 + kk + o0);
    }
    #pragma unroll
    for (int j = 0; j < 4; ++j) {
      int c = t + j * 256;
      int k = c >> 5, j4 = (c & 31) * 4;
      float4 v = *(const float4*)(Wv + (size_t)(kk + k) * 256 + ct * 128 + j4);
      Bv[j4 + 0][k] = (__bf16)v.x; Bv[j4 + 1][k] = (__bf16)v.y;
      Bv[j4 + 2][k] = (__bf16)v.z; Bv[j4 + 3][k] = (__bf16)v.w;
    }
    __syncthreads();
    s16x8 af[4], bfr[4];
    #pragma unroll
    for (int m = 0; m < 4; ++m)
      af[m] = *(const s16x8*)(&Am[wr * 64 + m * 16 + l15][l4 * 8]);
    #pragma unroll
    for (int nn = 0; nn < 4; ++nn)
      bfr[nn] = *(const s16x8*)(&Bv[wc * 64 + nn * 16 + l15][l4 * 8]);
    #pragma unroll
    for (int m = 0; m < 4; ++m)
      #pragma unroll
      for (int nn = 0; nn < 4; ++nn)
        acc[m][nn] = __builtin_amdgcn_mfma_f32_16x16x32_bf16(af[m], bfr[nn], acc[m][nn], 0, 0, 0);
    __syncthreads();
  }

  for (int m = 0; m < 4; ++m) {
    int row0 = rt * 128 + wr * 64 + m * 16 + l4 * 4;
    for (int nn = 0; nn < 4; ++nn) {
      int col = ct * 128 + wc * 64 + nn * 16 + l15;
      for (int r = 0; r < 4; ++r)
        Wcb[(size_t)(row0 + r) * 256 + col] = (__bf16)acc[m][nn][r];
    }
  }
}

// ---------- bc = Wm @ bv + bm (GEMV, one block per branch) -----------------
__global__ __launch_bounds__(256) void bc_kernel(
    const float* __restrict__ Wm0, const float* __restrict__ bv0,
    const float* __restrict__ bm0,
    const float* __restrict__ Wm1, const float* __restrict__ bv1,
    const float* __restrict__ bm1,
    float* __restrict__ bc0, float* __restrict__ bc1)
{
  const int br = blockIdx.x;
  const float* Wm = br ? Wm1 : Wm0;
  const float* bv = br ? bv1 : bv0;
  const float* bm = br ? bm1 : bm0;
  float* bc = br ? bc1 : bc0;
  __shared__ float bvl[256];
  const int t = threadIdx.x, lane = t & 63, w = t >> 6;
  bvl[t] = bv[t];
  __syncthreads();
  float b0 = bvl[lane * 4], b1 = bvl[lane * 4 + 1];
  float b2 = bvl[lane * 4 + 2], b3 = bvl[lane * 4 + 3];
  for (int i0 = 0; i0 < 64; i0 += 8) {
    float part[8];
    #pragma unroll
    for (int i = 0; i < 8; ++i) {
      int row = w * 64 + i0 + i;
      float4 a = *(const float4*)(Wm + (size_t)row * 256 + lane * 4);
      part[i] = a.x * b0 + a.y * b1 + a.z * b2 + a.w * b3;
    }
    #pragma unroll
    for (int i = 0; i < 8; ++i) {
      float s = part[i];
      for (int o = 1; o < 64; o <<= 1) s += __shfl_xor(s, o);
      int row = w * 64 + i0 + i;
      if (lane == 0) bc[row] = s + bm[row];
    }
  }
}

// ---------- Q/K projection GEMM (proven): C = A@Bw^T + bias, bf16 ----------
__global__ __launch_bounds__(256) void gemm_kernel(
    const float* __restrict__ A, const float* __restrict__ Bw,
    const float* __restrict__ bias, __bf16* __restrict__ C, int N)
{
  __shared__ __bf16 At[128 * 32];
  __shared__ __bf16 Bt[128 * 32];
  const int t = threadIdx.x;
  const int lane = t & 63, w = t >> 6;
  const int wr = w >> 1, wc = w & 1;
  const int l15 = lane & 15, l4 = lane >> 4;
  const int by = blockIdx.x, bx = blockIdx.y;

  f32x4 acc[4][4];
  for (int m = 0; m < 4; ++m)
    for (int nn = 0; nn < 4; ++nn) acc[m][nn] = (f32x4){0.f, 0.f, 0.f, 0.f};

  for (int kk = 0; kk < 256; kk += 32) {
    for (int j = 0; j < 2; ++j) {
      int c = t + j * 256;
      int row = c >> 2, off0 = (c & 3) * 8;
      *(s16x8*)(&At[row * 32 + off0]) = cvt8(A + (size_t)(by * 128 + row) * 256 + kk + off0);
      *(s16x8*)(&Bt[row * 32 + off0]) = cvt8(Bw + (size_t)(bx * 128 + row) * 256 + kk + off0);
    }
    __syncthreads();
    s16x8 af[4], bfr[4];
    for (int m = 0; m < 4; ++m)
      af[m] = *(const s16x8*)(&At[(wr * 64 + m * 16 + l15) * 32 + l4 * 8]);
    for (int nn = 0; nn < 4; ++nn)
      bfr[nn] = *(const s16x8*)(&Bt[(wc * 64 + nn * 16 + l15) * 32 + l4 * 8]);
    for (int m = 0; m < 4; ++m)
      for (int nn = 0; nn < 4; ++nn)
        acc[m][nn] = __builtin_amdgcn_mfma_f32_16x16x32_bf16(af[m], bfr[nn], acc[m][nn], 0, 0, 0);
    __syncthreads();
  }

  for (int m = 0; m < 4; ++m) {
    int row0 = by * 128 + wr * 64 + m * 16 + l4 * 4;
    for (int nn = 0; nn < 4; ++nn) {
      int col = bx * 128 + wc * 64 + nn * 16 + l15;
      float bc = bias[col];
      for (int r = 0; r < 4; ++r) {
        int row = row0 + r;
        C[(size_t)row * N + col] = (__bf16)(acc[m][nn][r] + bc);
      }
    }
  }
}

// ---------- VW projection: VWt tiled = Wc(bf16) @ rep^T + bc (row bias) ----
#define CTP 136
__global__ __launch_bounds__(256) void vgemmB_kernel(
    const __bf16* __restrict__ Ab, const float* __restrict__ Bw,
    const float* __restrict__ bias, __bf16* __restrict__ Vt, int total)
{
  __shared__ __bf16 At[128 * 32];
  __shared__ __bf16 Bt[128 * 32];
  __shared__ __bf16 Ct[128 * CTP];
  const int t = threadIdx.x;
  const int lane = t & 63, w = t >> 6;
  const int wr = w >> 1, wc = w & 1;
  const int l15 = lane & 15, l4 = lane >> 4;
  const int by = blockIdx.y;            // d-tile128 (0/1)
  const int bx = blockIdx.x;            // atom-tile128 -> XCD bx%8

  f32x4 acc[4][4];
  for (int m = 0; m < 4; ++m)
    for (int nn = 0; nn < 4; ++nn) acc[m][nn] = (f32x4){0.f, 0.f, 0.f, 0.f};

  for (int kk = 0; kk < 256; kk += 32) {
    for (int j = 0; j < 2; ++j) {
      int c = t + j * 256;
      int row = c >> 2, off0 = (c & 3) * 8;
      *(s16x8*)(&At[row * 32 + off0]) =
          *(const s16x8*)(Ab + (size_t)(by * 128 + row) * 256 + kk + off0);
      *(s16x8*)(&Bt[row * 32 + off0]) = cvt8(Bw + (size_t)(bx * 128 + row) * 256 + kk + off0);
    }
    __syncthreads();
    s16x8 af[4], bfr[4];
    for (int m = 0; m < 4; ++m)
      af[m] = *(const s16x8*)(&At[(wr * 64 + m * 16 + l15) * 32 + l4 * 8]);
    for (int nn = 0; nn < 4; ++nn)
      bfr[nn] = *(const s16x8*)(&Bt[(wc * 64 + nn * 16 + l15) * 32 + l4 * 8]);
    for (int m = 0; m < 4; ++m)
      for (int nn = 0; nn < 4; ++nn)
        acc[m][nn] = __builtin_amdgcn_mfma_f32_16x16x32_bf16(af[m], bfr[nn], acc[m][nn], 0, 0, 0);
    __syncthreads();
  }

  for (int m = 0; m < 4; ++m) {
    int rl0 = wr * 64 + m * 16 + l4 * 4;
    for (int nn = 0; nn < 4; ++nn) {
      int cl = wc * 64 + nn * 16 + l15;
      for (int r = 0; r < 4; ++r) {
        int rl = rl0 + r;
        Ct[rl * CTP + cl] = (__bf16)(acc[m][nn][r] + bias[by * 128 + rl]);
      }
    }
  }
  __syncthreads();

  for (int i = 0; i < 8; ++i) {
    int c = t + i * 256;
    int tile = c >> 5, w5 = c & 31;
    int kb_l = tile >> 3, db_l = tile & 7;
    int d_l = w5 & 15, kh = w5 >> 4;
    *(uint4*)(Vt + (((size_t)(bx * 8 + kb_l) * 16 + (by * 8 + db_l)) << 8) + w5 * 8) =
        *(const uint4*)(&Ct[(db_l * 16 + d_l) * CTP + kb_l * 16 + kh * 8]);
  }
}

// ---------- merged 2-way attention -> FINAL OUTPUT (gelu, fp32) ------------
struct Attn2Args {
  const __bf16* Q[2]; const __bf16* K[2]; const __bf16* V[2];
  unsigned long long O[2];              // float* out per branch
};
#define KP 264
#define PP 136
#define XFP 272
__global__ __launch_bounds__(512, 2) void attn2_kernel(
    Attn2Args args, const int* __restrict__ offs, const int* __restrict__ perm,
    int total)
{
  __shared__ __bf16 smem[128 * 136];              // 34816 B: K/P, then XTf
  __bf16 (*Klds)[KP] = (__bf16(*)[KP])smem;
  __bf16 (*Plds)[PP] = (__bf16(*)[PP])smem;
  float (*XTf)[XFP]  = (float(*)[XFP])smem;       // [32][272] fp32, aliases

  const int br = blockIdx.y;
  const __bf16* Q  = args.Q[br];
  const __bf16* Km = args.K[br];
  const __bf16* Vt = args.V[br];
  float* Out = (float*)args.O[br];

  const int g = perm[blockIdx.x];
  const int off = offs[g];
  const int n = offs[g + 1] - off;
  const int t = threadIdx.x, lane = t & 63, w = t >> 6;
  const int l15 = lane & 15, l4 = lane >> 4;
  const bool qact = (w * 16) < n;
  const bool big = (n > 64);

  const int srow = t >> 5, scol = (t & 31) * 16;
  uint4 kst[4];
  #pragma unroll
  for (int j = 0; j < 4; ++j)
    kst[j] = *(const uint4*)((const char*)(Km + (size_t)(off + j * 16 + srow) * 256) + scol);
  s16x8 qf[8];
  if (qact) {
    int qr = w * 16 + l15; if (qr >= n) qr = n - 1;
    const __bf16* qp = Q + (size_t)(off + qr) * 256 + l4 * 8;
    #pragma unroll
    for (int kk = 0; kk < 8; ++kk) qf[kk] = *(const s16x8*)(qp + kk * 32);
  }
  #pragma unroll
  for (int j = 0; j < 4; ++j)
    *(uint4*)((char*)&Klds[j * 16 + srow][0] + scol) = kst[j];
  uint4 kst1[4];
  if (big) {
    #pragma unroll
    for (int j = 0; j < 4; ++j)
      kst1[j] = *(const uint4*)((const char*)(Km + (size_t)(off + 64 + j * 16 + srow) * 256) + scol);
  }
  __syncthreads();

  f32x4 sacc[8];
  #pragma unroll
  for (int i = 0; i < 8; ++i) sacc[i] = (f32x4){0.f, 0.f, 0.f, 0.f};
  if (qact) {
    #pragma unroll
    for (int kt = 0; kt < 4; ++kt) {
      const __bf16* kp = &Klds[kt * 16 + l15][l4 * 8];
      #pragma unroll
      for (int kk = 0; kk < 8; ++kk) {
        s16x8 kf = *(const s16x8*)(kp + kk * 32);
        sacc[kt] = __builtin_amdgcn_mfma_f32_16x16x32_bf16(qf[kk], kf, sacc[kt], 0, 0, 0);
      }
    }
  }
  __syncthreads();
  if (big) {
    #pragma unroll
    for (int j = 0; j < 4; ++j)
      *(uint4*)((char*)&Klds[j * 16 + srow][0] + scol) = kst1[j];
    __syncthreads();
    if (qact) {
      #pragma unroll
      for (int kt = 0; kt < 4; ++kt) {
        const __bf16* kp = &Klds[kt * 16 + l15][l4 * 8];
        #pragma unroll
        for (int kk = 0; kk < 8; ++kk) {
          s16x8 kf = *(const s16x8*)(kp + kk * 32);
          sacc[4 + kt] = __builtin_amdgcn_mfma_f32_16x16x32_bf16(qf[kk], kf, sacc[4 + kt], 0, 0, 0);
        }
      }
    }
    __syncthreads();
  }

  if (qact) {
    #pragma unroll
    for (int r = 0; r < 4; ++r) {
      float sv[8];
      float m = -1e30f;
      #pragma unroll
      for (int kt = 0; kt < 8; ++kt) {
        int key = kt * 16 + l15;
        float v = (key < n) ? sacc[kt][r] * 0.0625f : -1e30f;
        sv[kt] = v; m = fmaxf(m, v);
      }
      for (int o = 1; o < 16; o <<= 1) m = fmaxf(m, __shfl_xor(m, o));
      float p[8], sum = 0.f;
      #pragma unroll
      for (int kt = 0; kt < 8; ++kt) { p[kt] = __expf(sv[kt] - m); sum += p[kt]; }
      for (int o = 1; o < 16; o <<= 1) sum += __shfl_xor(sum, o);
      float inv = 1.f / sum;
      int q = w * 16 + l4 * 4 + r;
      #pragma unroll
      for (int kt = 0; kt < 4; ++kt)
        Plds[q][kt * 16 + l15] = (__bf16)(p[kt] * inv);
      if (big) {
        #pragma unroll
        for (int kt = 4; kt < 8; ++kt)
          Plds[q][kt * 16 + l15] = (__bf16)(p[kt] * inv);
      }
    }
  }
  __syncthreads();

  const int dbase = w * 32;
  const int ktiles = total >> 4;
  f32x4 xacc[2][8];
  #pragma unroll
  for (int dt = 0; dt < 2; ++dt)
    #pragma unroll
    for (int qm = 0; qm < 8; ++qm) xacc[dt][qm] = (f32x4){0.f, 0.f, 0.f, 0.f};

  #pragma unroll
  for (int dt = 0; dt < 2; ++dt) {
    int db = w * 2 + dt;
    s16x8 vf[4];
    #pragma unroll
    for (int ks = 0; ks < 4; ++ks) {
      int kb = (off >> 4) + ks * 2 + (l4 >> 1);
      if (kb >= ktiles) kb = ktiles - 1;
      vf[ks] = *(const s16x8*)(Vt + (((size_t)kb * 16 + db) << 8)
                               + (l15 + ((l4 & 1) << 4)) * 8);
    }
    #pragma unroll
    for (int qm = 0; qm < 8; ++qm) {
      #pragma unroll
      for (int ks = 0; ks < 4; ++ks) {
        if (ks * 32 < n) {
          s16x8 pa = *(const s16x8*)(&Plds[qm * 16 + l15][ks * 32 + l4 * 8]);
          xacc[dt][qm] = __builtin_amdgcn_mfma_f32_16x16x32_bf16(pa, vf[ks], xacc[dt][qm], 0, 0, 0);
        }
      }
    }
  }
  __syncthreads();                                // Plds dead; XTf aliases

  // ---- epilogue: gelu + fp32 out via LDS bounce, 32-row rounds (full lines)
  for (int r0 = 0; r0 < 128; r0 += 32) {
    if (r0 >= n) break;                           // block-uniform
    int qmb = r0 >> 4;                            // rows [r0, r0+32): qm, qm+1
    #pragma unroll
    for (int dt = 0; dt < 2; ++dt)
      #pragma unroll
      for (int q2 = 0; q2 < 2; ++q2)
        #pragma unroll
        for (int r = 0; r < 4; ++r) {
          int lrow = q2 * 16 + l4 * 4 + r;
          XTf[lrow][dbase + dt * 16 + l15] = fast_gelu(xacc[dt][qmb + q2][r]);
        }
    __syncthreads();
    #pragma unroll
    for (int i = 0; i < 4; ++i) {
      int c = t + i * 512;                        // 2048 chunks: 32 rows x 64
      int row = c >> 6, seg = c & 63;
      if (r0 + row < n)
        *(uint4*)(Out + (size_t)(off + r0 + row) * 256 + seg * 4) =
            *(const uint4*)(&XTf[row][seg * 4]);
    }
    __syncthreads();
  }
}

// ---------------------------------------------------------------------------
extern "C" void kernel_launch(void* const* d_in, const int* in_sizes, int n_in,
                              void* d_out, int out_size, void* d_ws, size_t ws_size,
                              hipStream_t stream) {
  const float* rep2d = (const float*)d_in[0];
  const float* rep3d = (const float*)d_in[1];
  const int*   na    = (const int*)d_in[2];
  const float* wq23 = (const float*)d_in[3];  const float* bq23 = (const float*)d_in[4];
  const float* wk23 = (const float*)d_in[5];  const float* bk23 = (const float*)d_in[6];
  const float* wv23 = (const float*)d_in[7];  const float* bv23 = (const float*)d_in[8];
  const float* wq32 = (const float*)d_in[9];  const float* bq32 = (const float*)d_in[10];
  const float* wk32 = (const float*)d_in[11]; const float* bk32 = (const float*)d_in[12];
  const float* wv32 = (const float*)d_in[13]; const float* bv32 = (const float*)d_in[14];
  const float* wm23 = (const float*)d_in[15]; const float* bm23 = (const float*)d_in[16];
  const float* wm32 = (const float*)d_in[17]; const float* bm32 = (const float*)d_in[18];

  const int B = in_sizes[2];
  const int total = in_sizes[0] / 256;           // 40960
  float* out = (float*)d_out;

  char* ws = (char*)d_ws;
  const size_t SZ = (size_t)total * 256 * sizeof(__bf16);  // 20.97 MB
  const size_t WMB = 65536 * sizeof(__bf16);               // 128 KB
  const size_t need6 = 8192 + 2 * WMB + 6 * SZ;            // 126.1 MB (proven)
  const size_t need3 = 8192 + 2 * WMB + 3 * SZ;            // 63.2 MB (proven)
  int* offs = (int*)ws;                                    // [B+1]
  int* perm = (int*)(ws + 2560);                           // [B]
  float* bc0 = (float*)(ws + 5120);                        // [256]
  float* bc1 = (float*)(ws + 6144);                        // [256]

  dim3 blk(256);
  dim3 blkA(512);
  dim3 gP(total / 128, 2);
  dim3 gV(total / 128, 2);   // x = atom-tile (XCD aligned)

  if (ws_size >= need6) {
    __bf16* WC0 = (__bf16*)(ws + 8192);
    __bf16* WC1 = (__bf16*)(ws + 8192 + WMB);
    __bf16* BQ1 = (__bf16*)(ws + 8192 + 2 * WMB);
    __bf16* BK1 = (__bf16*)(ws + 8192 + 2 * WMB + SZ);
    __bf16* BV1 = (__bf16*)(ws + 8192 + 2 * WMB + 2 * SZ);
    __bf16* BQ2 = (__bf16*)(ws + 8192 + 2 * WMB + 3 * SZ);
    __bf16* BK2 = (__bf16*)(ws + 8192 + 2 * WMB + 4 * SZ);
    __bf16* BV2 = (__bf16*)(ws + 8192 + 2 * WMB + 5 * SZ);

    scan_kernel<<<1, 512, 0, stream>>>(na, offs, perm, B, total, out);
    wc_kernel<<<dim3(4, 2), blk, 0, stream>>>(wm23, wv23, wm32, wv32, WC0, WC1);
    bc_kernel<<<2, blk, 0, stream>>>(wm23, bv23, bm23, wm32, bv32, bm32, bc0, bc1);
    gemm_kernel<<<gP, blk, 0, stream>>>(rep2d, wq23, bq23, BQ1, 256);
    gemm_kernel<<<gP, blk, 0, stream>>>(rep3d, wk23, bk23, BK1, 256);
    vgemmB_kernel<<<gV, blk, 0, stream>>>(WC0, rep3d, bc0, BV1, total);
    gemm_kernel<<<gP, blk, 0, stream>>>(rep3d, wq32, bq32, BQ2, 256);
    gemm_kernel<<<gP, blk, 0, stream>>>(rep2d, wk32, bk32, BK2, 256);
    vgemmB_kernel<<<gV, blk, 0, stream>>>(WC1, rep2d, bc1, BV2, total);

    Attn2Args aa;
    aa.Q[0] = BQ1; aa.K[0] = BK1; aa.V[0] = BV1; aa.O[0] = (unsigned long long)out;
    aa.Q[1] = BQ2; aa.K[1] = BK2; aa.V[1] = BV2;
    aa.O[1] = (unsigned long long)(out + (size_t)total * 256);
    attn2_kernel<<<dim3(B, 2), blkA, 0, stream>>>(aa, offs, perm, total);
  } else if (ws_size >= need3) {
    __bf16* WC0 = (__bf16*)(ws + 8192);
    __bf16* WC1 = (__bf16*)(ws + 8192 + WMB);
    __bf16* BQ = (__bf16*)(ws + 8192 + 2 * WMB);
    __bf16* BK = (__bf16*)(ws + 8192 + 2 * WMB + SZ);
    __bf16* BV = (__bf16*)(ws + 8192 + 2 * WMB + 2 * SZ);

    scan_kernel<<<1, 512, 0, stream>>>(na, offs, perm, B, total, out);
    wc_kernel<<<dim3(4, 2), blk, 0, stream>>>(wm23, wv23, wm32, wv32, WC0, WC1);
    bc_kernel<<<2, blk, 0, stream>>>(wm23, bv23, bm23, wm32, bv32, bm32, bc0, bc1);
    for (int br = 0; br < 2; ++br) {
      const float* rq = br ? rep3d : rep2d;
      const float* rk = br ? rep2d : rep3d;
      const float* wq = br ? wq32 : wq23;  const float* bq = br ? bq32 : bq23;
      const float* wk = br ? wk32 : wk23;  const float* bk = br ? bk32 : bk23;
      __bf16* wcb = br ? WC1 : WC0;        float* bcv = br ? bc1 : bc0;
      float* o = out + (size_t)br * total * 256;

      gemm_kernel<<<gP, blk, 0, stream>>>(rq, wq, bq, BQ, 256);
      gemm_kernel<<<gP, blk, 0, stream>>>(rk, wk, bk, BK, 256);
      vgemmB_kernel<<<gV, blk, 0, stream>>>(wcb, rk, bcv, BV, total);
      Attn2Args aa;
      aa.Q[0] = BQ; aa.K[0] = BK; aa.V[0] = BV; aa.O[0] = (unsigned long long)o;
      aa.Q[1] = BQ; aa.K[1] = BK; aa.V[1] = BV; aa.O[1] = (unsigned long long)o;
      attn2_kernel<<<dim3(B, 1), blkA, 0, stream>>>(aa, offs, perm, total);
    }
  } else {
    sentinel_kernel<<<1, 64, 0, stream>>>(out, 54321.0f);
  }
}

// Round 21
// 214.678 us; speedup vs baseline: 1.3939x; 1.3939x over previous
//
#include <hip/hip_runtime.h>
#include <hip/hip_bf16.h>
#include <cstdint>

// ---------------------------------------------------------------------------
// InteractionMHA, fp32 I/O, bf16-MFMA compute.
// Identity (verified r19/r20): softmax rows sum to 1 =>
//   out = gelu(P @ (rep @ (Wm@Wv)^T + 1*bc^T)), bc = Wm@bv + bm.
// vgemmB projects rep through Wc=Wm@Wv; attn's PV accumulator IS the final
// output (gelu + fp32, LDS-bounced full-line stores).
// Round-21: r20's epilogue loop had a data-dependent break -> not unrolled ->
// xacc runtime-indexed -> SPILLED TO SCRATCH (VGPR=48, WRITE 338MB, 148us).
// Fixed: #pragma unroll rr=0..3 with block-uniform guards; indices static.
// ---------------------------------------------------------------------------

typedef short s16x8 __attribute__((ext_vector_type(8)));
typedef float f32x4 __attribute__((ext_vector_type(4)));

__device__ __forceinline__ s16x8 cvt8(const float* p) {
  float4 a0 = *(const float4*)p, a1 = *(const float4*)(p + 4);
  union { s16x8 v; __bf16 e[8]; } u;
  u.e[0] = (__bf16)a0.x; u.e[1] = (__bf16)a0.y; u.e[2] = (__bf16)a0.z; u.e[3] = (__bf16)a0.w;
  u.e[4] = (__bf16)a1.x; u.e[5] = (__bf16)a1.y; u.e[6] = (__bf16)a1.z; u.e[7] = (__bf16)a1.w;
  return u.v;
}
__device__ __forceinline__ float fast_gelu(float x) {
  float ax = fabsf(x);
  float t = 1.0f / (1.0f + 0.3275911f * (ax * 0.70710678f));
  float y = t * (0.254829592f + t * (-0.284496736f + t * (1.421413741f +
            t * (-1.453152027f + t * 1.061405429f))));
  float er = 1.0f - y * __expf(-0.5f * ax * ax);
  er = (x < 0.f) ? -er : er;
  return 0.5f * x * (1.0f + er);
}

__global__ void sentinel_kernel(float* out, float v) {
  if (threadIdx.x == 0 && blockIdx.x == 0) out[0] = v;
}

// ---------- scan + parallel XCD-affinity permutation (r18 proven) ----------
__global__ __launch_bounds__(512) void scan_kernel(
    const int* __restrict__ na, int* __restrict__ offs, int* __restrict__ perm,
    int B, int total, float* out)
{
  __shared__ int s32[512];
  __shared__ int s64[512];
  __shared__ uint4 sv[512];
  const int t = threadIdx.x;
  int v32 = 0, v64 = 0;
  if (t < B) {
    v32 = na[t];
    v64 = (int)((const long long*)na)[t];
  }
  s32[t] = v32; s64[t] = v64;
  __syncthreads();
  for (int o = 1; o < 512; o <<= 1) {
    int a = (t >= o) ? s32[t - o] : 0;
    int b = (t >= o) ? s64[t - o] : 0;
    __syncthreads();
    s32[t] += a; s64[t] += b;
    __syncthreads();
  }
  int tot32 = s32[B - 1], tot64 = s64[B - 1];
  bool ok32 = (tot32 == total), ok64 = (tot64 == total);
  int offv = ok32 ? (s32[t] - v32) : ok64 ? (s64[t] - v64) : 0;
  if (t < B) offs[t] = offv;
  if (t == 0) {
    offs[B] = ok32 ? tot32 : ok64 ? tot64 : 0;
    if (!ok32 && !ok64) out[0] = 31337.0f;
  }
  __syncthreads();

  const int key = (offv >> 7) & 7;
  uint4 oh = (uint4){0, 0, 0, 0};
  if (t < B) ((unsigned*)&oh)[key >> 1] = 1u << ((key & 1) * 16);
  sv[t] = oh;
  __syncthreads();
  for (int o = 1; o < 512; o <<= 1) {
    uint4 a = (t >= o) ? sv[t - o] : (uint4){0, 0, 0, 0};
    __syncthreads();
    sv[t].x += a.x; sv[t].y += a.y; sv[t].z += a.z; sv[t].w += a.w;
    __syncthreads();
  }
  uint4 totv = sv[B - 1];
  int count[8], cap[8];
  #pragma unroll
  for (int k = 0; k < 8; ++k) {
    count[k] = (((unsigned*)&totv)[k >> 1] >> ((k & 1) * 16)) & 0xFFFF;
    cap[k] = (k < B) ? ((B - 1 - k) / 8 + 1) : 0;
  }
  int rank = ((((unsigned*)&sv[t])[key >> 1] >> ((key & 1) * 16)) & 0xFFFF) - 1;
  bool lo = false;
  if (t < B) {
    if (rank < cap[key]) perm[key + 8 * rank] = t;
    else lo = true;
  }
  __syncthreads();
  s32[t] = lo ? 1 : 0;
  __syncthreads();
  for (int o = 1; o < 512; o <<= 1) {
    int a = (t >= o) ? s32[t - o] : 0;
    __syncthreads();
    s32[t] += a;
    __syncthreads();
  }
  if (lo) {
    int lr = s32[t] - 1;
    int used[8], eb = 0, k = 0, j = 0;
    #pragma unroll
    for (int q = 0; q < 8; ++q) used[q] = (count[q] < cap[q]) ? count[q] : cap[q];
    #pragma unroll
    for (int q = 0; q < 8; ++q) {
      int freeq = cap[q] - used[q];
      if (lr >= eb && lr < eb + freeq) { k = q; j = used[q] + (lr - eb); }
      eb += freeq;
    }
    perm[k + 8 * j] = t;
  }
}

// ---------- Wc = Wm @ Wv  (bf16 out; LDS-transposed Wv panel) --------------
__global__ __launch_bounds__(256) void wc_kernel(
    const float* __restrict__ Wm0, const float* __restrict__ Wv0,
    const float* __restrict__ Wm1, const float* __restrict__ Wv1,
    __bf16* __restrict__ Wcb0, __bf16* __restrict__ Wcb1)
{
  const int br = blockIdx.y;
  const float* Wm = br ? Wm1 : Wm0;
  const float* Wv = br ? Wv1 : Wv0;
  __bf16* Wcb = br ? Wcb1 : Wcb0;
  const int rt = blockIdx.x >> 1, ct = blockIdx.x & 1;
  __shared__ __bf16 Am[128][40];
  __shared__ __bf16 Bv[128][40];      // Bv[j][k] = Wv[kk+k][ct*128+j]
  const int t = threadIdx.x, lane = t & 63, w = t >> 6;
  const int wr = w >> 1, wc = w & 1;
  const int l15 = lane & 15, l4 = lane >> 4;

  f32x4 acc[4][4];
  for (int m = 0; m < 4; ++m)
    for (int nn = 0; nn < 4; ++nn) acc[m][nn] = (f32x4){0.f, 0.f, 0.f, 0.f};

  for (int kk = 0; kk < 256; kk += 32) {
    #pragma unroll
    for (int j = 0; j < 2; ++j) {
      int c = t + j * 256;
      int row = c >> 2, o0 = (c & 3) * 8;
      *(s16x8*)(&Am[row][o0]) = cvt8(Wm + (size_t)(rt * 128 + row) * 256 + kk + o0);
    }
    #pragma unroll
    for (int j = 0; j < 4; ++j) {
      int c = t + j * 256;
      int k = c >> 5, j4 = (c & 31) * 4;
      float4 v = *(const float4*)(Wv + (size_t)(kk + k) * 256 + ct * 128 + j4);
      Bv[j4 + 0][k] = (__bf16)v.x; Bv[j4 + 1][k] = (__bf16)v.y;
      Bv[j4 + 2][k] = (__bf16)v.z; Bv[j4 + 3][k] = (__bf16)v.w;
    }
    __syncthreads();
    s16x8 af[4], bfr[4];
    #pragma unroll
    for (int m = 0; m < 4; ++m)
      af[m] = *(const s16x8*)(&Am[wr * 64 + m * 16 + l15][l4 * 8]);
    #pragma unroll
    for (int nn = 0; nn < 4; ++nn)
      bfr[nn] = *(const s16x8*)(&Bv[wc * 64 + nn * 16 + l15][l4 * 8]);
    #pragma unroll
    for (int m = 0; m < 4; ++m)
      #pragma unroll
      for (int nn = 0; nn < 4; ++nn)
        acc[m][nn] = __builtin_amdgcn_mfma_f32_16x16x32_bf16(af[m], bfr[nn], acc[m][nn], 0, 0, 0);
    __syncthreads();
  }

  for (int m = 0; m < 4; ++m) {
    int row0 = rt * 128 + wr * 64 + m * 16 + l4 * 4;
    for (int nn = 0; nn < 4; ++nn) {
      int col = ct * 128 + wc * 64 + nn * 16 + l15;
      for (int r = 0; r < 4; ++r)
        Wcb[(size_t)(row0 + r) * 256 + col] = (__bf16)acc[m][nn][r];
    }
  }
}

// ---------- bc = Wm @ bv + bm (GEMV, one block per branch) -----------------
__global__ __launch_bounds__(256) void bc_kernel(
    const float* __restrict__ Wm0, const float* __restrict__ bv0,
    const float* __restrict__ bm0,
    const float* __restrict__ Wm1, const float* __restrict__ bv1,
    const float* __restrict__ bm1,
    float* __restrict__ bc0, float* __restrict__ bc1)
{
  const int br = blockIdx.x;
  const float* Wm = br ? Wm1 : Wm0;
  const float* bv = br ? bv1 : bv0;
  const float* bm = br ? bm1 : bm0;
  float* bc = br ? bc1 : bc0;
  __shared__ float bvl[256];
  const int t = threadIdx.x, lane = t & 63, w = t >> 6;
  bvl[t] = bv[t];
  __syncthreads();
  float b0 = bvl[lane * 4], b1 = bvl[lane * 4 + 1];
  float b2 = bvl[lane * 4 + 2], b3 = bvl[lane * 4 + 3];
  for (int i0 = 0; i0 < 64; i0 += 8) {
    float part[8];
    #pragma unroll
    for (int i = 0; i < 8; ++i) {
      int row = w * 64 + i0 + i;
      float4 a = *(const float4*)(Wm + (size_t)row * 256 + lane * 4);
      part[i] = a.x * b0 + a.y * b1 + a.z * b2 + a.w * b3;
    }
    #pragma unroll
    for (int i = 0; i < 8; ++i) {
      float s = part[i];
      for (int o = 1; o < 64; o <<= 1) s += __shfl_xor(s, o);
      int row = w * 64 + i0 + i;
      if (lane == 0) bc[row] = s + bm[row];
    }
  }
}

// ---------- Q/K projection GEMM (proven): C = A@Bw^T + bias, bf16 ----------
__global__ __launch_bounds__(256) void gemm_kernel(
    const float* __restrict__ A, const float* __restrict__ Bw,
    const float* __restrict__ bias, __bf16* __restrict__ C, int N)
{
  __shared__ __bf16 At[128 * 32];
  __shared__ __bf16 Bt[128 * 32];
  const int t = threadIdx.x;
  const int lane = t & 63, w = t >> 6;
  const int wr = w >> 1, wc = w & 1;
  const int l15 = lane & 15, l4 = lane >> 4;
  const int by = blockIdx.x, bx = blockIdx.y;

  f32x4 acc[4][4];
  for (int m = 0; m < 4; ++m)
    for (int nn = 0; nn < 4; ++nn) acc[m][nn] = (f32x4){0.f, 0.f, 0.f, 0.f};

  for (int kk = 0; kk < 256; kk += 32) {
    for (int j = 0; j < 2; ++j) {
      int c = t + j * 256;
      int row = c >> 2, off0 = (c & 3) * 8;
      *(s16x8*)(&At[row * 32 + off0]) = cvt8(A + (size_t)(by * 128 + row) * 256 + kk + off0);
      *(s16x8*)(&Bt[row * 32 + off0]) = cvt8(Bw + (size_t)(bx * 128 + row) * 256 + kk + off0);
    }
    __syncthreads();
    s16x8 af[4], bfr[4];
    for (int m = 0; m < 4; ++m)
      af[m] = *(const s16x8*)(&At[(wr * 64 + m * 16 + l15) * 32 + l4 * 8]);
    for (int nn = 0; nn < 4; ++nn)
      bfr[nn] = *(const s16x8*)(&Bt[(wc * 64 + nn * 16 + l15) * 32 + l4 * 8]);
    for (int m = 0; m < 4; ++m)
      for (int nn = 0; nn < 4; ++nn)
        acc[m][nn] = __builtin_amdgcn_mfma_f32_16x16x32_bf16(af[m], bfr[nn], acc[m][nn], 0, 0, 0);
    __syncthreads();
  }

  for (int m = 0; m < 4; ++m) {
    int row0 = by * 128 + wr * 64 + m * 16 + l4 * 4;
    for (int nn = 0; nn < 4; ++nn) {
      int col = bx * 128 + wc * 64 + nn * 16 + l15;
      float bc = bias[col];
      for (int r = 0; r < 4; ++r) {
        int row = row0 + r;
        C[(size_t)row * N + col] = (__bf16)(acc[m][nn][r] + bc);
      }
    }
  }
}

// ---------- VW projection: VWt tiled = Wc(bf16) @ rep^T + bc (row bias) ----
#define CTP 136
__global__ __launch_bounds__(256) void vgemmB_kernel(
    const __bf16* __restrict__ Ab, const float* __restrict__ Bw,
    const float* __restrict__ bias, __bf16* __restrict__ Vt, int total)
{
  __shared__ __bf16 At[128 * 32];
  __shared__ __bf16 Bt[128 * 32];
  __shared__ __bf16 Ct[128 * CTP];
  const int t = threadIdx.x;
  const int lane = t & 63, w = t >> 6;
  const int wr = w >> 1, wc = w & 1;
  const int l15 = lane & 15, l4 = lane >> 4;
  const int by = blockIdx.y;            // d-tile128 (0/1)
  const int bx = blockIdx.x;            // atom-tile128 -> XCD bx%8

  f32x4 acc[4][4];
  for (int m = 0; m < 4; ++m)
    for (int nn = 0; nn < 4; ++nn) acc[m][nn] = (f32x4){0.f, 0.f, 0.f, 0.f};

  for (int kk = 0; kk < 256; kk += 32) {
    for (int j = 0; j < 2; ++j) {
      int c = t + j * 256;
      int row = c >> 2, off0 = (c & 3) * 8;
      *(s16x8*)(&At[row * 32 + off0]) =
          *(const s16x8*)(Ab + (size_t)(by * 128 + row) * 256 + kk + off0);
      *(s16x8*)(&Bt[row * 32 + off0]) = cvt8(Bw + (size_t)(bx * 128 + row) * 256 + kk + off0);
    }
    __syncthreads();
    s16x8 af[4], bfr[4];
    for (int m = 0; m < 4; ++m)
      af[m] = *(const s16x8*)(&At[(wr * 64 + m * 16 + l15) * 32 + l4 * 8]);
    for (int nn = 0; nn < 4; ++nn)
      bfr[nn] = *(const s16x8*)(&Bt[(wc * 64 + nn * 16 + l15) * 32 + l4 * 8]);
    for (int m = 0; m < 4; ++m)
      for (int nn = 0; nn < 4; ++nn)
        acc[m][nn] = __builtin_amdgcn_mfma_f32_16x16x32_bf16(af[m], bfr[nn], acc[m][nn], 0, 0, 0);
    __syncthreads();
  }

  for (int m = 0; m < 4; ++m) {
    int rl0 = wr * 64 + m * 16 + l4 * 4;
    for (int nn = 0; nn < 4; ++nn) {
      int cl = wc * 64 + nn * 16 + l15;
      for (int r = 0; r < 4; ++r) {
        int rl = rl0 + r;
        Ct[rl * CTP + cl] = (__bf16)(acc[m][nn][r] + bias[by * 128 + rl]);
      }
    }
  }
  __syncthreads();

  for (int i = 0; i < 8; ++i) {
    int c = t + i * 256;
    int tile = c >> 5, w5 = c & 31;
    int kb_l = tile >> 3, db_l = tile & 7;
    int d_l = w5 & 15, kh = w5 >> 4;
    *(uint4*)(Vt + (((size_t)(bx * 8 + kb_l) * 16 + (by * 8 + db_l)) << 8) + w5 * 8) =
        *(const uint4*)(&Ct[(db_l * 16 + d_l) * CTP + kb_l * 16 + kh * 8]);
  }
}

// ---------- merged 2-way attention -> FINAL OUTPUT (gelu, fp32) ------------
struct Attn2Args {
  const __bf16* Q[2]; const __bf16* K[2]; const __bf16* V[2];
  unsigned long long O[2];              // float* out per branch
};
#define KP 264
#define PP 136
#define XFP 272
__global__ __launch_bounds__(512, 2) void attn2_kernel(
    Attn2Args args, const int* __restrict__ offs, const int* __restrict__ perm,
    int total)
{
  __shared__ __bf16 smem[128 * 136];              // 34816 B: K/P, then XTf
  __bf16 (*Klds)[KP] = (__bf16(*)[KP])smem;
  __bf16 (*Plds)[PP] = (__bf16(*)[PP])smem;
  float (*XTf)[XFP]  = (float(*)[XFP])smem;       // [32][272] fp32, aliases

  const int br = blockIdx.y;
  const __bf16* Q  = args.Q[br];
  const __bf16* Km = args.K[br];
  const __bf16* Vt = args.V[br];
  float* Out = (float*)args.O[br];

  const int g = perm[blockIdx.x];
  const int off = offs[g];
  const int n = offs[g + 1] - off;
  const int t = threadIdx.x, lane = t & 63, w = t >> 6;
  const int l15 = lane & 15, l4 = lane >> 4;
  const bool qact = (w * 16) < n;
  const bool big = (n > 64);

  const int srow = t >> 5, scol = (t & 31) * 16;
  uint4 kst[4];
  #pragma unroll
  for (int j = 0; j < 4; ++j)
    kst[j] = *(const uint4*)((const char*)(Km + (size_t)(off + j * 16 + srow) * 256) + scol);
  s16x8 qf[8];
  if (qact) {
    int qr = w * 16 + l15; if (qr >= n) qr = n - 1;
    const __bf16* qp = Q + (size_t)(off + qr) * 256 + l4 * 8;
    #pragma unroll
    for (int kk = 0; kk < 8; ++kk) qf[kk] = *(const s16x8*)(qp + kk * 32);
  }
  #pragma unroll
  for (int j = 0; j < 4; ++j)
    *(uint4*)((char*)&Klds[j * 16 + srow][0] + scol) = kst[j];
  uint4 kst1[4];
  if (big) {
    #pragma unroll
    for (int j = 0; j < 4; ++j)
      kst1[j] = *(const uint4*)((const char*)(Km + (size_t)(off + 64 + j * 16 + srow) * 256) + scol);
  }
  __syncthreads();

  f32x4 sacc[8];
  #pragma unroll
  for (int i = 0; i < 8; ++i) sacc[i] = (f32x4){0.f, 0.f, 0.f, 0.f};
  if (qact) {
    #pragma unroll
    for (int kt = 0; kt < 4; ++kt) {
      const __bf16* kp = &Klds[kt * 16 + l15][l4 * 8];
      #pragma unroll
      for (int kk = 0; kk < 8; ++kk) {
        s16x8 kf = *(const s16x8*)(kp + kk * 32);
        sacc[kt] = __builtin_amdgcn_mfma_f32_16x16x32_bf16(qf[kk], kf, sacc[kt], 0, 0, 0);
      }
    }
  }
  __syncthreads();
  if (big) {
    #pragma unroll
    for (int j = 0; j < 4; ++j)
      *(uint4*)((char*)&Klds[j * 16 + srow][0] + scol) = kst1[j];
    __syncthreads();
    if (qact) {
      #pragma unroll
      for (int kt = 0; kt < 4; ++kt) {
        const __bf16* kp = &Klds[kt * 16 + l15][l4 * 8];
        #pragma unroll
        for (int kk = 0; kk < 8; ++kk) {
          s16x8 kf = *(const s16x8*)(kp + kk * 32);
          sacc[4 + kt] = __builtin_amdgcn_mfma_f32_16x16x32_bf16(qf[kk], kf, sacc[4 + kt], 0, 0, 0);
        }
      }
    }
    __syncthreads();
  }

  if (qact) {
    #pragma unroll
    for (int r = 0; r < 4; ++r) {
      float sv[8];
      float m = -1e30f;
      #pragma unroll
      for (int kt = 0; kt < 8; ++kt) {
        int key = kt * 16 + l15;
        float v = (key < n) ? sacc[kt][r] * 0.0625f : -1e30f;
        sv[kt] = v; m = fmaxf(m, v);
      }
      for (int o = 1; o < 16; o <<= 1) m = fmaxf(m, __shfl_xor(m, o));
      float p[8], sum = 0.f;
      #pragma unroll
      for (int kt = 0; kt < 8; ++kt) { p[kt] = __expf(sv[kt] - m); sum += p[kt]; }
      for (int o = 1; o < 16; o <<= 1) sum += __shfl_xor(sum, o);
      float inv = 1.f / sum;
      int q = w * 16 + l4 * 4 + r;
      #pragma unroll
      for (int kt = 0; kt < 4; ++kt)
        Plds[q][kt * 16 + l15] = (__bf16)(p[kt] * inv);
      if (big) {
        #pragma unroll
        for (int kt = 4; kt < 8; ++kt)
          Plds[q][kt * 16 + l15] = (__bf16)(p[kt] * inv);
      }
    }
  }
  __syncthreads();

  const int dbase = w * 32;
  const int ktiles = total >> 4;
  f32x4 xacc[2][8];
  #pragma unroll
  for (int dt = 0; dt < 2; ++dt)
    #pragma unroll
    for (int qm = 0; qm < 8; ++qm) xacc[dt][qm] = (f32x4){0.f, 0.f, 0.f, 0.f};

  #pragma unroll
  for (int dt = 0; dt < 2; ++dt) {
    int db = w * 2 + dt;
    s16x8 vf[4];
    #pragma unroll
    for (int ks = 0; ks < 4; ++ks) {
      int kb = (off >> 4) + ks * 2 + (l4 >> 1);
      if (kb >= ktiles) kb = ktiles - 1;
      vf[ks] = *(const s16x8*)(Vt + (((size_t)kb * 16 + db) << 8)
                               + (l15 + ((l4 & 1) << 4)) * 8);
    }
    #pragma unroll
    for (int qm = 0; qm < 8; ++qm) {
      #pragma unroll
      for (int ks = 0; ks < 4; ++ks) {
        if (ks * 32 < n) {
          s16x8 pa = *(const s16x8*)(&Plds[qm * 16 + l15][ks * 32 + l4 * 8]);
          xacc[dt][qm] = __builtin_amdgcn_mfma_f32_16x16x32_bf16(pa, vf[ks], xacc[dt][qm], 0, 0, 0);
        }
      }
    }
  }
  __syncthreads();                                // Plds dead; XTf aliases

  // ---- epilogue: gelu + fp32 out via LDS bounce, 4 static 32-row rounds
  #pragma unroll
  for (int rr = 0; rr < 4; ++rr) {
    const int r0 = rr * 32;
    const bool act = (r0 < n);                    // block-uniform
    if (act) {
      #pragma unroll
      for (int dt = 0; dt < 2; ++dt)
        #pragma unroll
        for (int q2 = 0; q2 < 2; ++q2)
          #pragma unroll
          for (int r = 0; r < 4; ++r) {
            int lrow = q2 * 16 + l4 * 4 + r;
            XTf[lrow][dbase + dt * 16 + l15] = fast_gelu(xacc[dt][rr * 2 + q2][r]);
          }
    }
    __syncthreads();
    if (act) {
      #pragma unroll
      for (int i = 0; i < 4; ++i) {
        int c = t + i * 512;                      // 2048 chunks: 32 rows x 64
        int row = c >> 6, seg = c & 63;
        if (r0 + row < n)
          *(uint4*)(Out + (size_t)(off + r0 + row) * 256 + seg * 4) =
              *(const uint4*)(&XTf[row][seg * 4]);
      }
    }
    __syncthreads();
  }
}

// ---------------------------------------------------------------------------
extern "C" void kernel_launch(void* const* d_in, const int* in_sizes, int n_in,
                              void* d_out, int out_size, void* d_ws, size_t ws_size,
                              hipStream_t stream) {
  const float* rep2d = (const float*)d_in[0];
  const float* rep3d = (const float*)d_in[1];
  const int*   na    = (const int*)d_in[2];
  const float* wq23 = (const float*)d_in[3];  const float* bq23 = (const float*)d_in[4];
  const float* wk23 = (const float*)d_in[5];  const float* bk23 = (const float*)d_in[6];
  const float* wv23 = (const float*)d_in[7];  const float* bv23 = (const float*)d_in[8];
  const float* wq32 = (const float*)d_in[9];  const float* bq32 = (const float*)d_in[10];
  const float* wk32 = (const float*)d_in[11]; const float* bk32 = (const float*)d_in[12];
  const float* wv32 = (const float*)d_in[13]; const float* bv32 = (const float*)d_in[14];
  const float* wm23 = (const float*)d_in[15]; const float* bm23 = (const float*)d_in[16];
  const float* wm32 = (const float*)d_in[17]; const float* bm32 = (const float*)d_in[18];

  const int B = in_sizes[2];
  const int total = in_sizes[0] / 256;           // 40960
  float* out = (float*)d_out;

  char* ws = (char*)d_ws;
  const size_t SZ = (size_t)total * 256 * sizeof(__bf16);  // 20.97 MB
  const size_t WMB = 65536 * sizeof(__bf16);               // 128 KB
  const size_t need6 = 8192 + 2 * WMB + 6 * SZ;            // 126.1 MB (proven)
  const size_t need3 = 8192 + 2 * WMB + 3 * SZ;            // 63.2 MB (proven)
  int* offs = (int*)ws;                                    // [B+1]
  int* perm = (int*)(ws + 2560);                           // [B]
  float* bc0 = (float*)(ws + 5120);                        // [256]
  float* bc1 = (float*)(ws + 6144);                        // [256]

  dim3 blk(256);
  dim3 blkA(512);
  dim3 gP(total / 128, 2);
  dim3 gV(total / 128, 2);   // x = atom-tile (XCD aligned)

  if (ws_size >= need6) {
    __bf16* WC0 = (__bf16*)(ws + 8192);
    __bf16* WC1 = (__bf16*)(ws + 8192 + WMB);
    __bf16* BQ1 = (__bf16*)(ws + 8192 + 2 * WMB);
    __bf16* BK1 = (__bf16*)(ws + 8192 + 2 * WMB + SZ);
    __bf16* BV1 = (__bf16*)(ws + 8192 + 2 * WMB + 2 * SZ);
    __bf16* BQ2 = (__bf16*)(ws + 8192 + 2 * WMB + 3 * SZ);
    __bf16* BK2 = (__bf16*)(ws + 8192 + 2 * WMB + 4 * SZ);
    __bf16* BV2 = (__bf16*)(ws + 8192 + 2 * WMB + 5 * SZ);

    scan_kernel<<<1, 512, 0, stream>>>(na, offs, perm, B, total, out);
    wc_kernel<<<dim3(4, 2), blk, 0, stream>>>(wm23, wv23, wm32, wv32, WC0, WC1);
    bc_kernel<<<2, blk, 0, stream>>>(wm23, bv23, bm23, wm32, bv32, bm32, bc0, bc1);
    gemm_kernel<<<gP, blk, 0, stream>>>(rep2d, wq23, bq23, BQ1, 256);
    gemm_kernel<<<gP, blk, 0, stream>>>(rep3d, wk23, bk23, BK1, 256);
    vgemmB_kernel<<<gV, blk, 0, stream>>>(WC0, rep3d, bc0, BV1, total);
    gemm_kernel<<<gP, blk, 0, stream>>>(rep3d, wq32, bq32, BQ2, 256);
    gemm_kernel<<<gP, blk, 0, stream>>>(rep2d, wk32, bk32, BK2, 256);
    vgemmB_kernel<<<gV, blk, 0, stream>>>(WC1, rep2d, bc1, BV2, total);

    Attn2Args aa;
    aa.Q[0] = BQ1; aa.K[0] = BK1; aa.V[0] = BV1; aa.O[0] = (unsigned long long)out;
    aa.Q[1] = BQ2; aa.K[1] = BK2; aa.V[1] = BV2;
    aa.O[1] = (unsigned long long)(out + (size_t)total * 256);
    attn2_kernel<<<dim3(B, 2), blkA, 0, stream>>>(aa, offs, perm, total);
  } else if (ws_size >= need3) {
    __bf16* WC0 = (__bf16*)(ws + 8192);
    __bf16* WC1 = (__bf16*)(ws + 8192 + WMB);
    __bf16* BQ = (__bf16*)(ws + 8192 + 2 * WMB);
    __bf16* BK = (__bf16*)(ws + 8192 + 2 * WMB + SZ);
    __bf16* BV = (__bf16*)(ws + 8192 + 2 * WMB + 2 * SZ);

    scan_kernel<<<1, 512, 0, stream>>>(na, offs, perm, B, total, out);
    wc_kernel<<<dim3(4, 2), blk, 0, stream>>>(wm23, wv23, wm32, wv32, WC0, WC1);
    bc_kernel<<<2, blk, 0, stream>>>(wm23, bv23, bm23, wm32, bv32, bm32, bc0, bc1);
    for (int br = 0; br < 2; ++br) {
      const float* rq = br ? rep3d : rep2d;
      const float* rk = br ? rep2d : rep3d;
      const float* wq = br ? wq32 : wq23;  const float* bq = br ? bq32 : bq23;
      const float* wk = br ? wk32 : wk23;  const float* bk = br ? bk32 : bk23;
      __bf16* wcb = br ? WC1 : WC0;        float* bcv = br ? bc1 : bc0;
      float* o = out + (size_t)br * total * 256;

      gemm_kernel<<<gP, blk, 0, stream>>>(rq, wq, bq, BQ, 256);
      gemm_kernel<<<gP, blk, 0, stream>>>(rk, wk, bk, BK, 256);
      vgemmB_kernel<<<gV, blk, 0, stream>>>(wcb, rk, bcv, BV, total);
      Attn2Args aa;
      aa.Q[0] = BQ; aa.K[0] = BK; aa.V[0] = BV; aa.O[0] = (unsigned long long)o;
      aa.Q[1] = BQ; aa.K[1] = BK; aa.V[1] = BV; aa.O[1] = (unsigned long long)o;
      attn2_kernel<<<dim3(B, 1), blkA, 0, stream>>>(aa, offs, perm, total);
    }
  } else {
    sentinel_kernel<<<1, 64, 0, stream>>>(out, 54321.0f);
  }
}

// Round 22
// 204.431 us; speedup vs baseline: 1.4638x; 1.0501x over previous
//
#include <hip/hip_runtime.h>
#include <hip/hip_bf16.h>
#include <cstdint>

// ---------------------------------------------------------------------------
// InteractionMHA, fp32 I/O, bf16-MFMA compute.  (converged configuration)
//   scan+cvt (1 dispatch: block0 = offsets+XCD perm; blocks 1-64 = Wm->bf16)
//   4x gemm (Q/K, fp32 in, 5.7 TB/s proven)  2x vgemm (V, tiled 512B output)
//   attn2 (both branches, XCD-affine graph perm, half-staged K, tiled V reads,
//          bf16 X out via LDS bounce)          2x gemm_out (BK=64, bf16 Wm)
// Session walls (measured, resisted 6 intervention families): fp32-input
// gemms 5.7 TB/s; ws-bf16 consumers ~2-2.5 TB/s. All components at their wall.
// ---------------------------------------------------------------------------

typedef short s16x8 __attribute__((ext_vector_type(8)));
typedef float f32x4 __attribute__((ext_vector_type(4)));

__device__ __forceinline__ s16x8 cvt8(const float* p) {
  float4 a0 = *(const float4*)p, a1 = *(const float4*)(p + 4);
  union { s16x8 v; __bf16 e[8]; } u;
  u.e[0] = (__bf16)a0.x; u.e[1] = (__bf16)a0.y; u.e[2] = (__bf16)a0.z; u.e[3] = (__bf16)a0.w;
  u.e[4] = (__bf16)a1.x; u.e[5] = (__bf16)a1.y; u.e[6] = (__bf16)a1.z; u.e[7] = (__bf16)a1.w;
  return u.v;
}
__device__ __forceinline__ float fast_gelu(float x) {
  float ax = fabsf(x);
  float t = 1.0f / (1.0f + 0.3275911f * (ax * 0.70710678f));
  float y = t * (0.254829592f + t * (-0.284496736f + t * (1.421413741f +
            t * (-1.453152027f + t * 1.061405429f))));
  float er = 1.0f - y * __expf(-0.5f * ax * ax);
  er = (x < 0.f) ? -er : er;
  return 0.5f * x * (1.0f + er);
}

__global__ void sentinel_kernel(float* out, float v) {
  if (threadIdx.x == 0 && blockIdx.x == 0) out[0] = v;
}

// ---------- fused: block0 = scan + XCD perm; blocks 1..64 = Wm cvt ---------
__global__ __launch_bounds__(512) void scan_kernel(
    const int* __restrict__ na, int* __restrict__ offs, int* __restrict__ perm,
    int B, int total, float* out,
    const float* __restrict__ wm0, const float* __restrict__ wm1,
    __bf16* __restrict__ WM0, __bf16* __restrict__ WM1)
{
  if (blockIdx.x > 0) {                   // cvt duty (block-uniform select)
    int i = ((int)blockIdx.x - 1) * 2048 + threadIdx.x * 4;
    const float* in = (i < 65536) ? wm0 : wm1;
    __bf16* o = (i < 65536) ? WM0 : WM1;
    int j = i & 65535;
    float4 f = *(const float4*)(in + j);
    o[j + 0] = (__bf16)f.x; o[j + 1] = (__bf16)f.y;
    o[j + 2] = (__bf16)f.z; o[j + 3] = (__bf16)f.w;
    return;
  }
  __shared__ int s32[512];
  __shared__ int s64[512];
  __shared__ uint4 sv[512];
  const int t = threadIdx.x;
  int v32 = 0, v64 = 0;
  if (t < B) {
    v32 = na[t];
    v64 = (int)((const long long*)na)[t];
  }
  s32[t] = v32; s64[t] = v64;
  __syncthreads();
  for (int o = 1; o < 512; o <<= 1) {
    int a = (t >= o) ? s32[t - o] : 0;
    int b = (t >= o) ? s64[t - o] : 0;
    __syncthreads();
    s32[t] += a; s64[t] += b;
    __syncthreads();
  }
  int tot32 = s32[B - 1], tot64 = s64[B - 1];
  bool ok32 = (tot32 == total), ok64 = (tot64 == total);
  int offv = ok32 ? (s32[t] - v32) : ok64 ? (s64[t] - v64) : 0;
  if (t < B) offs[t] = offv;
  if (t == 0) {
    offs[B] = ok32 ? tot32 : ok64 ? tot64 : 0;
    if (!ok32 && !ok64) out[0] = 31337.0f;
  }
  __syncthreads();

  const int key = (offv >> 7) & 7;
  uint4 oh = (uint4){0, 0, 0, 0};
  if (t < B) ((unsigned*)&oh)[key >> 1] = 1u << ((key & 1) * 16);
  sv[t] = oh;
  __syncthreads();
  for (int o = 1; o < 512; o <<= 1) {
    uint4 a = (t >= o) ? sv[t - o] : (uint4){0, 0, 0, 0};
    __syncthreads();
    sv[t].x += a.x; sv[t].y += a.y; sv[t].z += a.z; sv[t].w += a.w;
    __syncthreads();
  }
  uint4 totv = sv[B - 1];
  int count[8], cap[8];
  #pragma unroll
  for (int k = 0; k < 8; ++k) {
    count[k] = (((unsigned*)&totv)[k >> 1] >> ((k & 1) * 16)) & 0xFFFF;
    cap[k] = (k < B) ? ((B - 1 - k) / 8 + 1) : 0;
  }
  int rank = ((((unsigned*)&sv[t])[key >> 1] >> ((key & 1) * 16)) & 0xFFFF) - 1;
  bool lo = false;
  if (t < B) {
    if (rank < cap[key]) perm[key + 8 * rank] = t;
    else lo = true;
  }
  __syncthreads();
  s32[t] = lo ? 1 : 0;
  __syncthreads();
  for (int o = 1; o < 512; o <<= 1) {
    int a = (t >= o) ? s32[t - o] : 0;
    __syncthreads();
    s32[t] += a;
    __syncthreads();
  }
  if (lo) {
    int lr = s32[t] - 1;
    int used[8], eb = 0, k = 0, j = 0;
    #pragma unroll
    for (int q = 0; q < 8; ++q) used[q] = (count[q] < cap[q]) ? count[q] : cap[q];
    #pragma unroll
    for (int q = 0; q < 8; ++q) {
      int freeq = cap[q] - used[q];
      if (lr >= eb && lr < eb + freeq) { k = q; j = used[q] + (lr - eb); }
      eb += freeq;
    }
    perm[k + 8 * j] = t;
  }
}

// ---------- Q/K projection GEMM (proven): C = A@Bw^T + bias, bf16 ----------
__global__ __launch_bounds__(256) void gemm_kernel(
    const float* __restrict__ A, const float* __restrict__ Bw,
    const float* __restrict__ bias, __bf16* __restrict__ C, int N)
{
  __shared__ __bf16 At[128 * 32];
  __shared__ __bf16 Bt[128 * 32];
  const int t = threadIdx.x;
  const int lane = t & 63, w = t >> 6;
  const int wr = w >> 1, wc = w & 1;
  const int l15 = lane & 15, l4 = lane >> 4;
  const int by = blockIdx.x, bx = blockIdx.y;

  f32x4 acc[4][4];
  for (int m = 0; m < 4; ++m)
    for (int nn = 0; nn < 4; ++nn) acc[m][nn] = (f32x4){0.f, 0.f, 0.f, 0.f};

  for (int kk = 0; kk < 256; kk += 32) {
    for (int j = 0; j < 2; ++j) {
      int c = t + j * 256;
      int row = c >> 2, off0 = (c & 3) * 8;
      *(s16x8*)(&At[row * 32 + off0]) = cvt8(A + (size_t)(by * 128 + row) * 256 + kk + off0);
      *(s16x8*)(&Bt[row * 32 + off0]) = cvt8(Bw + (size_t)(bx * 128 + row) * 256 + kk + off0);
    }
    __syncthreads();
    s16x8 af[4], bfr[4];
    for (int m = 0; m < 4; ++m)
      af[m] = *(const s16x8*)(&At[(wr * 64 + m * 16 + l15) * 32 + l4 * 8]);
    for (int nn = 0; nn < 4; ++nn)
      bfr[nn] = *(const s16x8*)(&Bt[(wc * 64 + nn * 16 + l15) * 32 + l4 * 8]);
    for (int m = 0; m < 4; ++m)
      for (int nn = 0; nn < 4; ++nn)
        acc[m][nn] = __builtin_amdgcn_mfma_f32_16x16x32_bf16(af[m], bfr[nn], acc[m][nn], 0, 0, 0);
    __syncthreads();
  }

  for (int m = 0; m < 4; ++m) {
    int row0 = by * 128 + wr * 64 + m * 16 + l4 * 4;
    for (int nn = 0; nn < 4; ++nn) {
      int col = bx * 128 + wc * 64 + nn * 16 + l15;
      float bc = bias[col];
      for (int r = 0; r < 4; ++r) {
        int row = row0 + r;
        C[(size_t)row * N + col] = (__bf16)(acc[m][nn][r] + bc);
      }
    }
  }
}

// ---------- V projection -> TILED layout; grid x = atom-tile (XCD align) ---
#define CTP 136
__global__ __launch_bounds__(256) void vgemm_kernel(
    const float* __restrict__ A, const float* __restrict__ Bw,
    const float* __restrict__ bias, __bf16* __restrict__ Vt, int total)
{
  __shared__ __bf16 At[128 * 32];
  __shared__ __bf16 Bt[128 * 32];
  __shared__ __bf16 Ct[128 * CTP];
  const int t = threadIdx.x;
  const int lane = t & 63, w = t >> 6;
  const int wr = w >> 1, wc = w & 1;
  const int l15 = lane & 15, l4 = lane >> 4;
  const int by = blockIdx.y;            // d-tile128 (0/1)
  const int bx = blockIdx.x;            // atom-tile128 -> XCD bx%8

  f32x4 acc[4][4];
  for (int m = 0; m < 4; ++m)
    for (int nn = 0; nn < 4; ++nn) acc[m][nn] = (f32x4){0.f, 0.f, 0.f, 0.f};

  for (int kk = 0; kk < 256; kk += 32) {
    for (int j = 0; j < 2; ++j) {
      int c = t + j * 256;
      int row = c >> 2, off0 = (c & 3) * 8;
      *(s16x8*)(&At[row * 32 + off0]) = cvt8(A + (size_t)(by * 128 + row) * 256 + kk + off0);
      *(s16x8*)(&Bt[row * 32 + off0]) = cvt8(Bw + (size_t)(bx * 128 + row) * 256 + kk + off0);
    }
    __syncthreads();
    s16x8 af[4], bfr[4];
    for (int m = 0; m < 4; ++m)
      af[m] = *(const s16x8*)(&At[(wr * 64 + m * 16 + l15) * 32 + l4 * 8]);
    for (int nn = 0; nn < 4; ++nn)
      bfr[nn] = *(const s16x8*)(&Bt[(wc * 64 + nn * 16 + l15) * 32 + l4 * 8]);
    for (int m = 0; m < 4; ++m)
      for (int nn = 0; nn < 4; ++nn)
        acc[m][nn] = __builtin_amdgcn_mfma_f32_16x16x32_bf16(af[m], bfr[nn], acc[m][nn], 0, 0, 0);
    __syncthreads();
  }

  for (int m = 0; m < 4; ++m) {
    int rl0 = wr * 64 + m * 16 + l4 * 4;
    for (int nn = 0; nn < 4; ++nn) {
      int cl = wc * 64 + nn * 16 + l15;
      for (int r = 0; r < 4; ++r) {
        int rl = rl0 + r;
        Ct[rl * CTP + cl] = (__bf16)(acc[m][nn][r] + bias[by * 128 + rl]);
      }
    }
  }
  __syncthreads();

  for (int i = 0; i < 8; ++i) {
    int c = t + i * 256;
    int tile = c >> 5, w5 = c & 31;
    int kb_l = tile >> 3, db_l = tile & 7;
    int d_l = w5 & 15, kh = w5 >> 4;
    *(uint4*)(Vt + (((size_t)(bx * 8 + kb_l) * 16 + (by * 8 + db_l)) << 8) + w5 * 8) =
        *(const uint4*)(&Ct[(db_l * 16 + d_l) * CTP + kb_l * 16 + kh * 8]);
  }
}

// ---------- merged 2-way attention, XCD-affine graph permutation -----------
struct Attn2Args {
  const __bf16* Q[2]; const __bf16* K[2]; const __bf16* V[2];
  unsigned long long X[2];
};
#define KP 264
#define PP 136
#define XP 272
__global__ __launch_bounds__(512, 2) void attn2_kernel(
    Attn2Args args, const int* __restrict__ offs, const int* __restrict__ perm,
    int total)
{
  __shared__ __bf16 smem[128 * 136];              // 34816 B, K/P/XT alias
  __bf16 (*Klds)[KP] = (__bf16(*)[KP])smem;
  __bf16 (*Plds)[PP] = (__bf16(*)[PP])smem;
  __bf16 (*XT)[XP]   = (__bf16(*)[XP])smem;

  const int br = blockIdx.y;
  const __bf16* Q  = args.Q[br];
  const __bf16* Km = args.K[br];
  const __bf16* Vt = args.V[br];
  __bf16* X = (__bf16*)args.X[br];

  const int g = perm[blockIdx.x];                 // XCD-affine assignment
  const int off = offs[g];
  const int n = offs[g + 1] - off;
  const int t = threadIdx.x, lane = t & 63, w = t >> 6;
  const int l15 = lane & 15, l4 = lane >> 4;
  const bool qact = (w * 16) < n;
  const bool big = (n > 64);

  const int srow = t >> 5, scol = (t & 31) * 16;
  uint4 kst[4];
  #pragma unroll
  for (int j = 0; j < 4; ++j)
    kst[j] = *(const uint4*)((const char*)(Km + (size_t)(off + j * 16 + srow) * 256) + scol);
  s16x8 qf[8];
  if (qact) {
    int qr = w * 16 + l15; if (qr >= n) qr = n - 1;
    const __bf16* qp = Q + (size_t)(off + qr) * 256 + l4 * 8;
    #pragma unroll
    for (int kk = 0; kk < 8; ++kk) qf[kk] = *(const s16x8*)(qp + kk * 32);
  }
  #pragma unroll
  for (int j = 0; j < 4; ++j)
    *(uint4*)((char*)&Klds[j * 16 + srow][0] + scol) = kst[j];
  uint4 kst1[4];
  if (big) {
    #pragma unroll
    for (int j = 0; j < 4; ++j)
      kst1[j] = *(const uint4*)((const char*)(Km + (size_t)(off + 64 + j * 16 + srow) * 256) + scol);
  }
  __syncthreads();

  f32x4 sacc[8];
  #pragma unroll
  for (int i = 0; i < 8; ++i) sacc[i] = (f32x4){0.f, 0.f, 0.f, 0.f};
  if (qact) {
    #pragma unroll
    for (int kt = 0; kt < 4; ++kt) {
      const __bf16* kp = &Klds[kt * 16 + l15][l4 * 8];
      #pragma unroll
      for (int kk = 0; kk < 8; ++kk) {
        s16x8 kf = *(const s16x8*)(kp + kk * 32);
        sacc[kt] = __builtin_amdgcn_mfma_f32_16x16x32_bf16(qf[kk], kf, sacc[kt], 0, 0, 0);
      }
    }
  }
  __syncthreads();
  if (big) {
    #pragma unroll
    for (int j = 0; j < 4; ++j)
      *(uint4*)((char*)&Klds[j * 16 + srow][0] + scol) = kst1[j];
    __syncthreads();
    if (qact) {
      #pragma unroll
      for (int kt = 0; kt < 4; ++kt) {
        const __bf16* kp = &Klds[kt * 16 + l15][l4 * 8];
        #pragma unroll
        for (int kk = 0; kk < 8; ++kk) {
          s16x8 kf = *(const s16x8*)(kp + kk * 32);
          sacc[4 + kt] = __builtin_amdgcn_mfma_f32_16x16x32_bf16(qf[kk], kf, sacc[4 + kt], 0, 0, 0);
        }
      }
    }
    __syncthreads();
  }

  if (qact) {
    #pragma unroll
    for (int r = 0; r < 4; ++r) {
      float sv[8];
      float m = -1e30f;
      #pragma unroll
      for (int kt = 0; kt < 8; ++kt) {
        int key = kt * 16 + l15;
        float v = (key < n) ? sacc[kt][r] * 0.0625f : -1e30f;
        sv[kt] = v; m = fmaxf(m, v);
      }
      for (int o = 1; o < 16; o <<= 1) m = fmaxf(m, __shfl_xor(m, o));
      float p[8], sum = 0.f;
      #pragma unroll
      for (int kt = 0; kt < 8; ++kt) { p[kt] = __expf(sv[kt] - m); sum += p[kt]; }
      for (int o = 1; o < 16; o <<= 1) sum += __shfl_xor(sum, o);
      float inv = 1.f / sum;
      int q = w * 16 + l4 * 4 + r;
      #pragma unroll
      for (int kt = 0; kt < 4; ++kt)
        Plds[q][kt * 16 + l15] = (__bf16)(p[kt] * inv);
      if (big) {
        #pragma unroll
        for (int kt = 4; kt < 8; ++kt)
          Plds[q][kt * 16 + l15] = (__bf16)(p[kt] * inv);
      }
    }
  }
  __syncthreads();

  const int dbase = w * 32;
  const int ktiles = total >> 4;
  f32x4 xacc[2][8];
  #pragma unroll
  for (int dt = 0; dt < 2; ++dt)
    #pragma unroll
    for (int qm = 0; qm < 8; ++qm) xacc[dt][qm] = (f32x4){0.f, 0.f, 0.f, 0.f};

  #pragma unroll
  for (int dt = 0; dt < 2; ++dt) {
    int db = w * 2 + dt;
    s16x8 vf[4];
    #pragma unroll
    for (int ks = 0; ks < 4; ++ks) {
      int kb = (off >> 4) + ks * 2 + (l4 >> 1);
      if (kb >= ktiles) kb = ktiles - 1;
      vf[ks] = *(const s16x8*)(Vt + (((size_t)kb * 16 + db) << 8)
                               + (l15 + ((l4 & 1) << 4)) * 8);
    }
    #pragma unroll
    for (int qm = 0; qm < 8; ++qm) {
      #pragma unroll
      for (int ks = 0; ks < 4; ++ks) {
        if (ks * 32 < n) {
          s16x8 pa = *(const s16x8*)(&Plds[qm * 16 + l15][ks * 32 + l4 * 8]);
          xacc[dt][qm] = __builtin_amdgcn_mfma_f32_16x16x32_bf16(pa, vf[ks], xacc[dt][qm], 0, 0, 0);
        }
      }
    }
  }
  __syncthreads();

  #pragma unroll
  for (int dt = 0; dt < 2; ++dt)
    #pragma unroll
    for (int qm = 0; qm < 4; ++qm)
      #pragma unroll
      for (int r = 0; r < 4; ++r)
        XT[qm * 16 + l4 * 4 + r][dbase + dt * 16 + l15] = (__bf16)xacc[dt][qm][r];
  __syncthreads();
  #pragma unroll
  for (int i = 0; i < 4; ++i) {
    int c = t + i * 512;
    int row = c >> 5, seg = c & 31;
    if (row < n)
      *(uint4*)(X + (size_t)(off + row) * 256 + seg * 8) =
          *(const uint4*)(&XT[row][seg * 8]);
  }
  if (big) {
    __syncthreads();
    #pragma unroll
    for (int dt = 0; dt < 2; ++dt)
      #pragma unroll
      for (int qm = 4; qm < 8; ++qm)
        #pragma unroll
        for (int r = 0; r < 4; ++r)
          XT[(qm - 4) * 16 + l4 * 4 + r][dbase + dt * 16 + l15] = (__bf16)xacc[dt][qm][r];
    __syncthreads();
    #pragma unroll
    for (int i = 0; i < 4; ++i) {
      int c = t + i * 512;
      int row = c >> 5, seg = c & 31;
      int grow = 64 + row;
      if (grow < n)
        *(uint4*)(X + (size_t)(off + grow) * 256 + seg * 8) =
            *(const uint4*)(&XT[row][seg * 8]);
    }
  }
}

// ---------- out-proj (64x128, BK=64, bf16 Wm, XCD-affine row swizzle) ------
#define OP 88
__global__ __launch_bounds__(256) void gemm_out(
    const __bf16* __restrict__ A, const __bf16* __restrict__ W,
    const float* __restrict__ bias, float* __restrict__ C, int swz)
{
  __shared__ __bf16 At[64 * OP];
  __shared__ __bf16 Bt[128 * OP];
  const int t = threadIdx.x;
  const int lane = t & 63, w = t >> 6;
  const int wr = w >> 1, wc = w & 1;
  const int l15 = lane & 15, l4 = lane >> 4;
  int b = blockIdx.x, by;
  if (swz) {
    int k = b & 7, q = b >> 3;
    by = ((k + ((q >> 1) << 3)) << 1) | (q & 1);
  } else by = b;
  const int bx = blockIdx.y;

  f32x4 acc[2][4];
  for (int m = 0; m < 2; ++m)
    for (int nn = 0; nn < 4; ++nn) acc[m][nn] = (f32x4){0.f, 0.f, 0.f, 0.f};

  for (int kk = 0; kk < 256; kk += 64) {
    #pragma unroll
    for (int j = 0; j < 2; ++j) {
      int c = t + j * 256;
      int row = c >> 3, off0 = (c & 7) * 8;
      *(s16x8*)(&At[row * OP + off0]) =
          *(const s16x8*)(A + (size_t)(by * 64 + row) * 256 + kk + off0);
    }
    #pragma unroll
    for (int j = 0; j < 4; ++j) {
      int c = t + j * 256;
      int row = c >> 3, off0 = (c & 7) * 8;
      *(s16x8*)(&Bt[row * OP + off0]) =
          *(const s16x8*)(W + (size_t)(bx * 128 + row) * 256 + kk + off0);
    }
    __syncthreads();
    #pragma unroll
    for (int k2 = 0; k2 < 2; ++k2) {
      s16x8 af[2], bfr[4];
      #pragma unroll
      for (int m = 0; m < 2; ++m)
        af[m] = *(const s16x8*)(&At[(wr * 32 + m * 16 + l15) * OP + k2 * 32 + l4 * 8]);
      #pragma unroll
      for (int nn = 0; nn < 4; ++nn)
        bfr[nn] = *(const s16x8*)(&Bt[(wc * 64 + nn * 16 + l15) * OP + k2 * 32 + l4 * 8]);
      #pragma unroll
      for (int m = 0; m < 2; ++m)
        #pragma unroll
        for (int nn = 0; nn < 4; ++nn)
          acc[m][nn] = __builtin_amdgcn_mfma_f32_16x16x32_bf16(af[m], bfr[nn], acc[m][nn], 0, 0, 0);
    }
    __syncthreads();
  }

  for (int m = 0; m < 2; ++m) {
    int row0 = by * 64 + wr * 32 + m * 16 + l4 * 4;
    for (int nn = 0; nn < 4; ++nn) {
      int col = bx * 128 + wc * 64 + nn * 16 + l15;
      float bc = bias[col];
      for (int r = 0; r < 4; ++r) {
        int row = row0 + r;
        C[(size_t)row * 256 + col] = fast_gelu(acc[m][nn][r] + bc);
      }
    }
  }
}

// ---------------------------------------------------------------------------
extern "C" void kernel_launch(void* const* d_in, const int* in_sizes, int n_in,
                              void* d_out, int out_size, void* d_ws, size_t ws_size,
                              hipStream_t stream) {
  const float* rep2d = (const float*)d_in[0];
  const float* rep3d = (const float*)d_in[1];
  const int*   na    = (const int*)d_in[2];
  const float* wq23 = (const float*)d_in[3];  const float* bq23 = (const float*)d_in[4];
  const float* wk23 = (const float*)d_in[5];  const float* bk23 = (const float*)d_in[6];
  const float* wv23 = (const float*)d_in[7];  const float* bv23 = (const float*)d_in[8];
  const float* wq32 = (const float*)d_in[9];  const float* bq32 = (const float*)d_in[10];
  const float* wk32 = (const float*)d_in[11]; const float* bk32 = (const float*)d_in[12];
  const float* wv32 = (const float*)d_in[13]; const float* bv32 = (const float*)d_in[14];
  const float* wm23 = (const float*)d_in[15]; const float* bm23 = (const float*)d_in[16];
  const float* wm32 = (const float*)d_in[17]; const float* bm32 = (const float*)d_in[18];

  const int B = in_sizes[2];
  const int total = in_sizes[0] / 256;           // 40960
  float* out = (float*)d_out;

  char* ws = (char*)d_ws;
  const size_t SZ = (size_t)total * 256 * sizeof(__bf16);  // 20.97 MB
  const size_t WMB = 65536 * sizeof(__bf16);               // 128 KB
  const size_t need6 = 8192 + 2 * WMB + 6 * SZ;            // 126.1 MB (proven)
  const size_t need3 = 8192 + 2 * WMB + 3 * SZ;            // 63.2 MB (proven)
  int* offs = (int*)ws;                                    // [B+1]
  int* perm = (int*)(ws + 4096);                           // [B]

  dim3 blk(256);
  dim3 blkA(512);
  dim3 gP(total / 128, 2);
  dim3 gV(total / 128, 2);   // x = atom-tile (XCD aligned)
  dim3 gO(total / 64, 2);
  const int swz = ((total / 64) % 16 == 0) ? 1 : 0;

  if (ws_size >= need6) {
    __bf16* WM0 = (__bf16*)(ws + 8192);
    __bf16* WM1 = (__bf16*)(ws + 8192 + WMB);
    __bf16* BQ1 = (__bf16*)(ws + 8192 + 2 * WMB);
    __bf16* BK1 = (__bf16*)(ws + 8192 + 2 * WMB + SZ);
    __bf16* BV1 = (__bf16*)(ws + 8192 + 2 * WMB + 2 * SZ);
    __bf16* BQ2 = (__bf16*)(ws + 8192 + 2 * WMB + 3 * SZ);
    __bf16* BK2 = (__bf16*)(ws + 8192 + 2 * WMB + 4 * SZ);
    __bf16* BV2 = (__bf16*)(ws + 8192 + 2 * WMB + 5 * SZ);

    scan_kernel<<<65, 512, 0, stream>>>(na, offs, perm, B, total, out,
                                        wm23, wm32, WM0, WM1);
    gemm_kernel<<<gP, blk, 0, stream>>>(rep2d, wq23, bq23, BQ1, 256);
    gemm_kernel<<<gP, blk, 0, stream>>>(rep3d, wk23, bk23, BK1, 256);
    vgemm_kernel<<<gV, blk, 0, stream>>>(wv23, rep3d, bv23, BV1, total);
    gemm_kernel<<<gP, blk, 0, stream>>>(rep3d, wq32, bq32, BQ2, 256);
    gemm_kernel<<<gP, blk, 0, stream>>>(rep2d, wk32, bk32, BK2, 256);
    vgemm_kernel<<<gV, blk, 0, stream>>>(wv32, rep2d, bv32, BV2, total);

    Attn2Args aa;
    aa.Q[0] = BQ1; aa.K[0] = BK1; aa.V[0] = BV1; aa.X[0] = (unsigned long long)BQ1;
    aa.Q[1] = BQ2; aa.K[1] = BK2; aa.V[1] = BV2; aa.X[1] = (unsigned long long)BQ2;
    attn2_kernel<<<dim3(B, 2), blkA, 0, stream>>>(aa, offs, perm, total);

    gemm_out<<<gO, blk, 0, stream>>>(BQ1, WM0, bm23, out, swz);
    gemm_out<<<gO, blk, 0, stream>>>(BQ2, WM1, bm32, out + (size_t)total * 256, swz);
  } else if (ws_size >= need3) {
    __bf16* WM0 = (__bf16*)(ws + 8192);
    __bf16* WM1 = (__bf16*)(ws + 8192 + WMB);
    __bf16* BQ = (__bf16*)(ws + 8192 + 2 * WMB);
    __bf16* BK = (__bf16*)(ws + 8192 + 2 * WMB + SZ);
    __bf16* BV = (__bf16*)(ws + 8192 + 2 * WMB + 2 * SZ);

    scan_kernel<<<65, 512, 0, stream>>>(na, offs, perm, B, total, out,
                                        wm23, wm32, WM0, WM1);
    for (int br = 0; br < 2; ++br) {
      const float* rq = br ? rep3d : rep2d;
      const float* rk = br ? rep2d : rep3d;
      const float* wq = br ? wq32 : wq23;  const float* bq = br ? bq32 : bq23;
      const float* wk = br ? wk32 : wk23;  const float* bk = br ? bk32 : bk23;
      const float* wv = br ? wv32 : wv23;  const float* bv = br ? bv32 : bv23;
      __bf16* wm = br ? WM1 : WM0;         const float* bm = br ? bm32 : bm23;
      float* o = out + (size_t)br * total * 256;

      gemm_kernel<<<gP, blk, 0, stream>>>(rq, wq, bq, BQ, 256);
      gemm_kernel<<<gP, blk, 0, stream>>>(rk, wk, bk, BK, 256);
      vgemm_kernel<<<gV, blk, 0, stream>>>(wv, rk, bv, BV, total);
      Attn2Args aa;
      aa.Q[0] = BQ; aa.K[0] = BK; aa.V[0] = BV; aa.X[0] = (unsigned long long)BQ;
      aa.Q[1] = BQ; aa.K[1] = BK; aa.V[1] = BV; aa.X[1] = (unsigned long long)BQ;
      attn2_kernel<<<dim3(B, 1), blkA, 0, stream>>>(aa, offs, perm, total);
      gemm_out<<<gO, blk, 0, stream>>>(BQ, wm, bm, o, swz);
    }
  } else {
    sentinel_kernel<<<1, 64, 0, stream>>>(out, 54321.0f);
  }
}